// Round 5
// baseline (2268.956 us; speedup 1.0000x reference)
//
#include <hip/hip_runtime.h>
#include <cstdint>
#include <cstddef>

// Problem constants
#define B_    16
#define T_    32
#define H_    512
#define P_    1024        // 32*32 spatial
#define NPOS  16384       // B_*P_
#define NG    2048        // 4*H_

typedef __attribute__((ext_vector_type(8))) short short8;
typedef __attribute__((ext_vector_type(4))) float f32x4;

__device__ __forceinline__ unsigned short f2bf(float f) {
  uint32_t u = __float_as_uint(f);
  u += 0x7fffu + ((u >> 16) & 1u);     // RNE
  return (unsigned short)(u >> 16);
}
__device__ __forceinline__ float bflo(uint32_t u) { return __uint_as_float(u << 16); }
__device__ __forceinline__ float bfhi(uint32_t u) { return __uint_as_float(u & 0xffff0000u); }

__device__ __forceinline__ float sigf(float x) {
  return __builtin_amdgcn_rcpf(1.0f + __expf(-x));
}
__device__ __forceinline__ float tanhf_(float x) {
  return 1.0f - 2.0f * __builtin_amdgcn_rcpf(__expf(2.0f * x) + 1.0f);
}

__device__ __forceinline__ void gload_lds16(const void* g, void* l) {
  __builtin_amdgcn_global_load_lds(
      (const __attribute__((address_space(1))) void*)g,
      (__attribute__((address_space(3))) void*)l, 16, 0, 0);
}

// ---------------- repack kernels ----------------
// Wp[r][k] = bf16(Wc[o][1+k]),  r = ch*4+g,  o = g*512+ch  (k-contiguous rows)
__global__ void repack_w(const float* __restrict__ Wc, const float* __restrict__ bconv,
                         unsigned short* __restrict__ Wp, float* __restrict__ w0x,
                         float* __restrict__ bx) {
  int idx = blockIdx.x * 256 + threadIdx.x;       // 2048*512 exact
  int r = idx >> 9, k = idx & 511;
  int ch = r >> 2, g = r & 3;
  int o = g * 512 + ch;
  Wp[idx] = f2bf(Wc[o * 513 + 1 + k]);
  if (k == 0) { w0x[r] = Wc[o * 513]; bx[r] = bconv[o]; }
}

// wpp[j][c] = W_post[0][c][j],  j = dy*3+dx  (c-contiguous)
__global__ void repack_wpost(const float* __restrict__ Wpost, float* __restrict__ wpp) {
  int idx = blockIdx.x * 256 + threadIdx.x;
  if (idx >= 9 * 512) return;
  int j = idx >> 9, c = idx & 511;
  wpp[idx] = Wpost[c * 9 + j];
}

// ---------------- fused gates-GEMM + LSTM pointwise ----------------
// m201-style fine-grained schedule (the actual lever, not coarse dbuf):
// K=512 streamed as 16 half-tiles (K=32) through a RING OF 4 LDS slots
// (4x16KB A + 4x16KB B = 128 KB). Each half = 2 phases:
//   { <=8 ds_read_b128 | 2 global_load_lds (half h+3) | s_barrier |
//     setprio(1) 16 MFMA setprio(0) | s_barrier }
// Staging runs 3 halves ahead; per-half wait is s_waitcnt vmcnt(8) (NEVER 0
// until the tail) => ~2500 cyc of load-latency cover, and waves flow into the
// next phase's ds_reads while the matrix pipe drains the previous cluster.
// Round 4 (coarse phases: all-stage/all-read/all-MFMA windows) was the m196
// anti-pattern and ran 57 us; intra-half barriers here are pure schedule
// locks -- every cross-wave hazard settles at a half boundary (slot reused
// only 3 halves after its last read).
__global__ __launch_bounds__(512, 2)
void lstm_step(const unsigned short* __restrict__ Wp,
               const unsigned short* __restrict__ hprev,
               unsigned short* __restrict__ hnext,
               _Float16* __restrict__ Cst,
               const float* __restrict__ w0x, const float* __restrict__ bxv,
               const float* __restrict__ xin, int t) {
  __shared__ unsigned short As[4 * 256 * 32];   // 64 KB: ring of 4 K-half slots (W)
  __shared__ unsigned short Bs[4 * 256 * 32];   // 64 KB: ring of 4 K-half slots (h)

  const int tid = threadIdx.x;
  const int lane = tid & 63;
  const int wv = tid >> 6;                  // 0..7
  const int wm = wv >> 2, wn = wv & 3;      // 2x4 waves over 256x256 tile
  const int q = lane >> 4, l = lane & 15;

  // T1 XCD swizzle (verified: FETCH 76 -> 33 MB): each XCD gets 8 contiguous
  // position-tiles x all 8 row-tiles -> h (2 MB) + W (2 MB) L2-resident.
  const int bid = blockIdx.x;               // 0..511
  const int xcd = bid & 7;
  const int sl  = bid >> 3;                 // 0..63
  const int ny  = xcd * 8 + (sl & 7);       // 0..63 position-tile
  const int rx  = sl >> 3;                  // 0..7  row-tile
  const int r0  = rx * 256;
  const int n0  = ny * 256;

  // staging geometry: issue j (0/1) of wave wv covers LDS bytes
  // slot*16384 + j*8192 + wv*1024 + lane*16  ->  row j*128 + wv*16 + (lane>>2),
  // stored chunk lane&3. Stored chunk c holds global chunk c ^ (row&3)
  // (pre-swizzled source, linear DMA dest -- rule #21).
  const int rr = wv * 16 + (lane >> 2);     // 0..127
  const int gchunk = (lane & 3) ^ (rr & 3); // row&3 == rr&3 for both j (j*128 % 4 == 0)
  const unsigned short* gAsrc = Wp    + (size_t)(r0 + rr) * 512 + gchunk * 8;
  const unsigned short* gBsrc = hprev + (size_t)(n0 + rr) * 512 + gchunk * 8;
  char* ldA = (char*)As + wv * 1024;        // + slot*16384 + j*8192 (wave-uniform)
  char* ldB = (char*)Bs + wv * 1024;

  auto stageA = [&](int hf) {
    char* d = ldA + (hf & 3) * 16384;
    gload_lds16(gAsrc + hf * 32, d);
    gload_lds16(gAsrc + 128 * 512 + hf * 32, d + 8192);
  };
  auto stageB = [&](int hf) {
    char* d = ldB + (hf & 3) * 16384;
    gload_lds16(gBsrc + hf * 32, d);
    gload_lds16(gBsrc + 128 * 512 + hf * 32, d + 8192);
  };

  f32x4 acc[8][4] = {};

  // fragment byte-offset within a row: chunk q stored at q ^ (row&3); for
  // rows base+l (base mult of 16), row&3 == l&3 -> lane-constant.
  const int cxb = (q ^ (l & 3)) << 4;

  // prologue: halves 0,1,2 in flight (12 gloads); wait half 0 (vmcnt(8))
  stageA(0); stageB(0); stageA(1); stageB(1); stageA(2); stageB(2);
  asm volatile("s_waitcnt vmcnt(8)" ::: "memory");
  __builtin_amdgcn_s_barrier();

#pragma unroll
  for (int h = 0; h < 16; ++h) {
    const char* Ah = (const char*)As + (h & 3) * 16384;
    const char* Bh = (const char*)Bs + (h & 3) * 16384;

    // ---- phase A: read A mi0-3 + B ni0-3, stage A-half of h+3, MFMA Q-top ----
    short8 a0[4], b_[4];
#pragma unroll
    for (int mi = 0; mi < 4; ++mi) {
      int row = wm * 128 + mi * 16 + l;
      a0[mi] = *(const short8*)(Ah + row * 64 + cxb);
    }
#pragma unroll
    for (int ni = 0; ni < 4; ++ni) {
      int row = wn * 64 + ni * 16 + l;
      b_[ni] = *(const short8*)(Bh + row * 64 + cxb);
    }
    if (h + 3 < 16) stageA(h + 3);
    __builtin_amdgcn_s_barrier();
    __builtin_amdgcn_s_setprio(1);
#pragma unroll
    for (int mi = 0; mi < 4; ++mi)
#pragma unroll
      for (int ni = 0; ni < 4; ++ni)
        acc[mi][ni] = __builtin_amdgcn_mfma_f32_16x16x32_bf16(a0[mi], b_[ni], acc[mi][ni], 0, 0, 0);
    __builtin_amdgcn_s_setprio(0);
    __builtin_amdgcn_s_barrier();

    // ---- phase B: read A mi4-7, stage B-half of h+3, boundary vmcnt, MFMA Q-bot ----
    short8 a1[4];
#pragma unroll
    for (int mi = 0; mi < 4; ++mi) {
      int row = wm * 128 + (mi + 4) * 16 + l;
      a1[mi] = *(const short8*)(Ah + row * 64 + cxb);
    }
    if (h + 3 < 16) stageB(h + 3);
    // boundary: ensure half h+1 landed before next iter reads it.
    // in-flight (worst): h+1, h+2, h+3 = 12 loads -> wait <=8 keeps 2 halves
    // in flight; tail: h=13 -> 4, h=14 -> 0 (only drain, issued 1 half ago).
    if (h <= 12)      asm volatile("s_waitcnt vmcnt(8)" ::: "memory");
    else if (h == 13) asm volatile("s_waitcnt vmcnt(4)" ::: "memory");
    else if (h == 14) asm volatile("s_waitcnt vmcnt(0)" ::: "memory");
    __builtin_amdgcn_s_barrier();
    __builtin_amdgcn_s_setprio(1);
#pragma unroll
    for (int mi = 0; mi < 4; ++mi)
#pragma unroll
      for (int ni = 0; ni < 4; ++ni)
        acc[mi + 4][ni] = __builtin_amdgcn_mfma_f32_16x16x32_bf16(a1[mi], b_[ni], acc[mi + 4][ni], 0, 0, 0);
    __builtin_amdgcn_s_setprio(0);
    __builtin_amdgcn_s_barrier();
  }

  // ---- epilogue: lane's 4 regs of acc[mi][ni] = (i,f,o,g) for one (ch,pos) ----
  float xv[4]; int posL[4]; size_t cbase[4];
#pragma unroll
  for (int ni = 0; ni < 4; ++ni) {
    posL[ni] = wn * 64 + ni * 16 + l;        // 0..255
    int pos = n0 + posL[ni];
    int b = pos >> 10, p = pos & 1023;
    xv[ni] = xin[((b * T_ + t) << 10) + p];
    cbase[ni] = ((size_t)b << 19) + p;       // b*512*1024 + p
  }
  const int ch0 = rx * 64;
#pragma unroll
  for (int mi = 0; mi < 8; ++mi) {
    int chl = wm * 32 + mi * 4 + q;                    // local ch 0..63
    int rg = r0 + wm * 128 + mi * 16 + q * 4;          // global row of reg0
    float4 w0 = *(const float4*)(w0x + rg);
    float4 bb = *(const float4*)(bxv + rg);
    int ch = ch0 + chl;
#pragma unroll
    for (int ni = 0; ni < 4; ++ni) {
      f32x4 g = acc[mi][ni];
      float gi = g[0] + w0.x * xv[ni] + bb.x;
      float gf = g[1] + w0.y * xv[ni] + bb.y;
      float go = g[2] + w0.z * xv[ni] + bb.z;
      float gg = g[3] + w0.w * xv[ni] + bb.w;
      size_t cidx = cbase[ni] + ((size_t)ch << 10);
      float cold = (float)Cst[cidx];
      float cn = sigf(gf) * cold + sigf(gi) + tanhf_(gg);
      float hn = sigf(go) + tanhf_(cn);
      Cst[cidx] = (_Float16)cn;
      // stash into As slots 0-1 (32 KB; last reads were slots 2,3 = h14,h15
      // -- disjoint). Chunk-XOR swizzle (verified: conflicts 4.1M -> 327K).
      As[posL[ni] * 64 + (chl ^ ((posL[ni] & 7) << 3))] = f2bf(hn);
    }
  }
  __syncthreads();
  {
    int pl = tid >> 1;                 // 0..255 local pos
    int cb = (tid & 1) << 2;           // chunk base: 0 or 4 (8-short chunks)
    const unsigned short* srcrow = As + pl * 64;
    unsigned short* dst = hnext + (size_t)(n0 + pl) * 512 + ch0 + (cb << 3);
#pragma unroll
    for (int i = 0; i < 4; ++i)
      ((uint4*)dst)[i] = *(const uint4*)(srcrow + (((cb + i) ^ (pl & 7)) << 3));
  }
}

// ---------------- 3x3 post conv (512ch -> 1) ----------------
// one wave per output pixel; lane covers 8 channels
__global__ __launch_bounds__(256)
void post_conv(const unsigned short* __restrict__ h, const float* __restrict__ wpp,
               const float* __restrict__ bpost, float* __restrict__ out, int t) {
  int wid = blockIdx.x * 4 + (threadIdx.x >> 6);   // 0..16383
  int lane = threadIdx.x & 63;
  int b = wid >> 10, p = wid & 1023;
  int py = p >> 5, px = p & 31;
  int c0 = lane << 3;
  float acc = 0.f;
#pragma unroll
  for (int dy = -1; dy <= 1; ++dy) {
    int ny = py + dy;
    if ((unsigned)ny > 31u) continue;
#pragma unroll
    for (int dx = -1; dx <= 1; ++dx) {
      int nx = px + dx;
      if ((unsigned)nx > 31u) continue;
      int j = (dy + 1) * 3 + (dx + 1);
      const uint4 hv = *(const uint4*)(h + ((size_t)((b << 10) + (ny << 5) + nx) << 9) + c0);
      const float4 wa = *(const float4*)(wpp + (j << 9) + c0);
      const float4 wb = *(const float4*)(wpp + (j << 9) + c0 + 4);
      acc += bflo(hv.x) * wa.x + bfhi(hv.x) * wa.y
           + bflo(hv.y) * wa.z + bfhi(hv.y) * wa.w
           + bflo(hv.z) * wb.x + bfhi(hv.z) * wb.y
           + bflo(hv.w) * wb.z + bfhi(hv.w) * wb.w;
    }
  }
#pragma unroll
  for (int off = 1; off < 64; off <<= 1)
    acc += __shfl_xor(acc, off, 64);
  if (lane == 0)
    out[((b * T_ + t) << 10) + p] = acc + bpost[0];
}

// ---------------- launch ----------------
extern "C" void kernel_launch(void* const* d_in, const int* in_sizes, int n_in,
                              void* d_out, int out_size, void* d_ws, size_t ws_size,
                              hipStream_t stream) {
  const float* x     = (const float*)d_in[0];
  const float* Wconv = (const float*)d_in[1];
  const float* bconv = (const float*)d_in[2];
  const float* Wpost = (const float*)d_in[3];
  const float* bpost = (const float*)d_in[4];
  float* out = (float*)d_out;
  char* ws = (char*)d_ws;

  // workspace layout (bytes)
  unsigned short* h0  = (unsigned short*)(ws);                 // 16 MB
  unsigned short* h1  = (unsigned short*)(ws + 16777216);      // 16 MB
  _Float16*       Cst = (_Float16*)(ws + 33554432);            // 16 MB (fp16 state)
  unsigned short* Wp  = (unsigned short*)(ws + 50331648);      // 2 MB
  float*          w0x = (float*)(ws + 52428800);               // 8 KB
  float*          bx  = (float*)(ws + 52436992);               // 8 KB
  float*          wpp = (float*)(ws + 52445184);               // 18 KB

  hipMemsetAsync(h0, 0, 16777216, stream);
  hipMemsetAsync(Cst, 0, 16777216, stream);
  repack_w<<<4096, 256, 0, stream>>>(Wconv, bconv, Wp, w0x, bx);
  repack_wpost<<<18, 256, 0, stream>>>(Wpost, wpp);

  unsigned short* hp = h0;
  unsigned short* hn = h1;
  for (int t = 0; t < T_; ++t) {
    lstm_step<<<512, 512, 0, stream>>>(Wp, hp, hn, Cst, w0x, bx, x, t);
    post_conv<<<4096, 256, 0, stream>>>(hn, wpp, bpost, out, t);
    unsigned short* tmp = hp; hp = hn; hn = tmp;
  }
}

// Round 6
// 1975.138 us; speedup vs baseline: 1.1488x; 1.1488x over previous
//
#include <hip/hip_runtime.h>
#include <cstdint>
#include <cstddef>

// Problem constants
#define B_    16
#define T_    32
#define H_    512
#define P_    1024        // 32*32 spatial
#define NPOS  16384       // B_*P_
#define NG    2048        // 4*H_

typedef __attribute__((ext_vector_type(8))) short short8;
typedef __attribute__((ext_vector_type(4))) float f32x4;

__device__ __forceinline__ unsigned short f2bf(float f) {
  uint32_t u = __float_as_uint(f);
  u += 0x7fffu + ((u >> 16) & 1u);     // RNE
  return (unsigned short)(u >> 16);
}
__device__ __forceinline__ float bflo(uint32_t u) { return __uint_as_float(u << 16); }
__device__ __forceinline__ float bfhi(uint32_t u) { return __uint_as_float(u & 0xffff0000u); }

__device__ __forceinline__ float sigf(float x) {
  return __builtin_amdgcn_rcpf(1.0f + __expf(-x));
}
__device__ __forceinline__ float tanhf_(float x) {
  return 1.0f - 2.0f * __builtin_amdgcn_rcpf(__expf(2.0f * x) + 1.0f);
}

__device__ __forceinline__ void gload_lds16(const void* g, void* l) {
  __builtin_amdgcn_global_load_lds(
      (const __attribute__((address_space(1))) void*)g,
      (__attribute__((address_space(3))) void*)l, 16, 0, 0);
}

// ---------------- repack kernels ----------------
// Wp[r][k] = bf16(Wc[o][1+k]),  r = ch*4+g,  o = g*512+ch  (k-contiguous rows)
__global__ void repack_w(const float* __restrict__ Wc, const float* __restrict__ bconv,
                         unsigned short* __restrict__ Wp, float* __restrict__ w0x,
                         float* __restrict__ bx) {
  int idx = blockIdx.x * 256 + threadIdx.x;       // 2048*512 exact
  int r = idx >> 9, k = idx & 511;
  int ch = r >> 2, g = r & 3;
  int o = g * 512 + ch;
  Wp[idx] = f2bf(Wc[o * 513 + 1 + k]);
  if (k == 0) { w0x[r] = Wc[o * 513]; bx[r] = bconv[o]; }
}

// wpp[j][c] = W_post[0][c][j],  j = dy*3+dx  (c-contiguous)
__global__ void repack_wpost(const float* __restrict__ Wpost, float* __restrict__ wpp) {
  int idx = blockIdx.x * 256 + threadIdx.x;
  if (idx >= 9 * 512) return;
  int j = idx >> 9, c = idx & 511;
  wpp[idx] = Wpost[c * 9 + j];
}

// ---------------- fused gates-GEMM + LSTM pointwise ----------------
// R0 structure (verified best: 256x128 tile, 4 waves, 48 KB single-buffer LDS,
// 3 blocks/CU = 3 waves/SIMD, 2-barrier K-loop). 6 rounds of schedule variants
// (dbuf, coarse/fine 8-phase, counted vmcnt) all lost to this at fixed
// occupancy -- with K=512 there are only 8 K-iters/block, so deep pipelines
// can't amortize. Changes vs R0: (a) T1 XCD swizzle (verified in R4:
// FETCH 76->33 MB): each XCD owns 16 pos-tiles x 8 row-tiles so W (2 MB) and
// its h slice (2 MB) stay L2-resident; (b) epilogue stash XOR-swizzle
// (verified: conflicts 4.13M -> 327K). launch_bounds stays (256,2) -- R3's
// (,3) squeezed VGPR 92->84 and cost ~3 us.
__global__ __launch_bounds__(256, 2)
void lstm_step(const unsigned short* __restrict__ Wp,
               const unsigned short* __restrict__ hprev,
               unsigned short* __restrict__ hnext,
               _Float16* __restrict__ Cst,
               const float* __restrict__ w0x, const float* __restrict__ bxv,
               const float* __restrict__ xin, int t) {
  __shared__ unsigned short As[256 * 64];   // W tile   [row r][k], XOR-swizzled chunks (32 KB)
  __shared__ unsigned short Bs[128 * 64];   // h tile   [pos][k],   XOR-swizzled chunks (16 KB)

  const int tid = threadIdx.x;
  const int lane = tid & 63;
  const int wv = tid >> 6;
  const int wm = wv >> 1, wn = wv & 1;      // 2x2 waves over 256x128 tile
  const int q = lane >> 4, l = lane & 15;

  // T1 XCD swizzle: linear id round-robins XCDs (dispatch-order heuristic);
  // give each XCD 16 contiguous pos-tiles x all 8 row-tiles.
  const int lid = blockIdx.x;               // 0..1023
  const int xcd = lid & 7;
  const int s   = lid >> 3;                 // 0..127
  const int ny  = xcd * 16 + (s & 15);      // pos-tile 0..127
  const int rx  = s >> 4;                   // row-tile 0..7
  const int r0  = rx * 256;                 // gate-row base
  const int n0  = ny * 128;                 // position base
  const int ch0 = rx * 64;

  // staging map: lds byte j*4096 + tid*16 -> row j*32 + (tid>>3), stored chunk tid&7
  const int srow = tid >> 3;
  const int lchunk = (tid & 7) ^ (srow & 7);
  const unsigned short* gA = Wp    + (size_t)(r0 + srow) * 512 + lchunk * 8;
  const unsigned short* gB = hprev + (size_t)(n0 + srow) * 512 + lchunk * 8;
  char* lA = (char*)As + wv * 1024;
  char* lB = (char*)Bs + wv * 1024;

  f32x4 acc[8][4] = {};

  for (int kc = 0; kc < 512; kc += 64) {
#pragma unroll
    for (int j = 0; j < 8; ++j)
      gload_lds16(gA + (size_t)j * (32 * 512) + kc, lA + j * 4096);
#pragma unroll
    for (int j = 0; j < 4; ++j)
      gload_lds16(gB + (size_t)j * (32 * 512) + kc, lB + j * 4096);
    __syncthreads();

#pragma unroll
    for (int kk = 0; kk < 2; ++kk) {
      short8 af[8], bf_[4];
#pragma unroll
      for (int mi = 0; mi < 8; ++mi) {
        int row = wm * 128 + mi * 16 + l;
        int sidx = row * 64 + (((kk * 4 + q) ^ (row & 7)) * 8);
        af[mi] = *(const short8*)(As + sidx);
      }
#pragma unroll
      for (int ni = 0; ni < 4; ++ni) {
        int row = wn * 64 + ni * 16 + l;
        int sidx = row * 64 + (((kk * 4 + q) ^ (row & 7)) * 8);
        bf_[ni] = *(const short8*)(Bs + sidx);
      }
#pragma unroll
      for (int mi = 0; mi < 8; ++mi)
#pragma unroll
        for (int ni = 0; ni < 4; ++ni)
          acc[mi][ni] = __builtin_amdgcn_mfma_f32_16x16x32_bf16(af[mi], bf_[ni], acc[mi][ni], 0, 0, 0);
    }
    __syncthreads();
  }

  // ---- epilogue: lane's 4 regs of acc[mi][ni] = (i,f,o,g) for one (ch,pos) ----
  float xv[4]; int posL[4]; size_t cbase[4];
#pragma unroll
  for (int ni = 0; ni < 4; ++ni) {
    posL[ni] = wn * 64 + ni * 16 + l;
    int pos = n0 + posL[ni];
    int b = pos >> 10, p = pos & 1023;
    xv[ni] = xin[((b * T_ + t) << 10) + p];
    cbase[ni] = ((size_t)b << 19) + p;    // b*512*1024 + p
  }
#pragma unroll
  for (int mi = 0; mi < 8; ++mi) {
    int chl = wm * 32 + mi * 4 + q;                    // local ch 0..63
    int rg = r0 + wm * 128 + mi * 16 + q * 4;          // global row of reg0
    float4 w0 = *(const float4*)(w0x + rg);
    float4 bb = *(const float4*)(bxv + rg);
    int ch = ch0 + chl;
#pragma unroll
    for (int ni = 0; ni < 4; ++ni) {
      f32x4 g = acc[mi][ni];
      float gi = g[0] + w0.x * xv[ni] + bb.x;
      float gf = g[1] + w0.y * xv[ni] + bb.y;
      float go = g[2] + w0.z * xv[ni] + bb.z;
      float gg = g[3] + w0.w * xv[ni] + bb.w;
      size_t cidx = cbase[ni] + ((size_t)ch << 10);
      float cold = (float)Cst[cidx];
      float cn = sigf(gf) * cold + sigf(gi) + tanhf_(gg);
      float hn = sigf(go) + tanhf_(cn);
      Cst[cidx] = (_Float16)cn;
      // stash for coalesced store, chunk-XOR swizzled (verified 327K conflicts)
      As[posL[ni] * 64 + (chl ^ ((posL[ni] & 7) << 3))] = f2bf(hn);
    }
  }
  __syncthreads();
  {
    int pl = tid >> 1;                 // 0..127 local pos
    int cb = (tid & 1) << 2;           // chunk base: 0 or 4 (8-short chunks)
    const unsigned short* srcrow = As + pl * 64;
    unsigned short* dst = hnext + (size_t)(n0 + pl) * 512 + ch0 + (cb << 3);
#pragma unroll
    for (int i = 0; i < 4; ++i)
      ((uint4*)dst)[i] = *(const uint4*)(srcrow + (((cb + i) ^ (pl & 7)) << 3));
  }
}

// ---------------- post conv, decomposed ----------------
// out[p] = b + sum_j sum_c h[p+d_j][c] * wpp[j][c]
//        = b + sum_j u[j][p+d_j],   u[j][p] = dot_c(h[p], wpp[j]).
// Old post_conv read h 9x (144 MB L2/step, 12 us). conv_u reads h ONCE
// (16 MB), conv_st reads u (590 KB). One wave per pixel; lane owns 8 ch.
__global__ __launch_bounds__(256)
void conv_u(const unsigned short* __restrict__ h, const float* __restrict__ wpp,
            float* __restrict__ u) {
  int wid = blockIdx.x * 4 + (threadIdx.x >> 6);   // pos 0..16383
  int lane = threadIdx.x & 63;
  int c0 = lane << 3;
  const uint4 hv = *(const uint4*)(h + ((size_t)wid << 9) + c0);
  float hc0 = bflo(hv.x), hc1 = bfhi(hv.x), hc2 = bflo(hv.y), hc3 = bfhi(hv.y);
  float hc4 = bflo(hv.z), hc5 = bfhi(hv.z), hc6 = bflo(hv.w), hc7 = bfhi(hv.w);
  int b = wid >> 10, p = wid & 1023;
  float outv = 0.f;
#pragma unroll
  for (int j = 0; j < 9; ++j) {
    const float4 wa = *(const float4*)(wpp + (j << 9) + c0);
    const float4 wb = *(const float4*)(wpp + (j << 9) + c0 + 4);
    float a = hc0 * wa.x + hc1 * wa.y + hc2 * wa.z + hc3 * wa.w
            + hc4 * wb.x + hc5 * wb.y + hc6 * wb.z + hc7 * wb.w;
#pragma unroll
    for (int off = 1; off < 64; off <<= 1)
      a += __shfl_xor(a, off, 64);
    if (lane == j) outv = a;             // static index; lane j keeps u_j
  }
  if (lane < 9)
    u[((b * 9 + lane) << 10) + p] = outv;
}

__global__ __launch_bounds__(256)
void conv_st(const float* __restrict__ u, const float* __restrict__ bpost,
             float* __restrict__ out, int t) {
  int idx = blockIdx.x * 256 + threadIdx.x;        // 0..16383
  int b = idx >> 10, p = idx & 1023;
  int py = p >> 5, px = p & 31;
  float acc = bpost[0];
#pragma unroll
  for (int dy = -1; dy <= 1; ++dy) {
    int ny = py + dy;
    if ((unsigned)ny > 31u) continue;
#pragma unroll
    for (int dx = -1; dx <= 1; ++dx) {
      int nx = px + dx;
      if ((unsigned)nx > 31u) continue;
      int j = (dy + 1) * 3 + (dx + 1);
      acc += u[((b * 9 + j) << 10) + (ny << 5) + nx];
    }
  }
  out[((b * T_ + t) << 10) + p] = acc;
}

// ---------------- launch ----------------
extern "C" void kernel_launch(void* const* d_in, const int* in_sizes, int n_in,
                              void* d_out, int out_size, void* d_ws, size_t ws_size,
                              hipStream_t stream) {
  const float* x     = (const float*)d_in[0];
  const float* Wconv = (const float*)d_in[1];
  const float* bconv = (const float*)d_in[2];
  const float* Wpost = (const float*)d_in[3];
  const float* bpost = (const float*)d_in[4];
  float* out = (float*)d_out;
  char* ws = (char*)d_ws;

  // workspace layout (bytes)
  unsigned short* h0  = (unsigned short*)(ws);                 // 16 MB
  unsigned short* h1  = (unsigned short*)(ws + 16777216);      // 16 MB
  _Float16*       Cst = (_Float16*)(ws + 33554432);            // 16 MB (fp16 state)
  unsigned short* Wp  = (unsigned short*)(ws + 50331648);      // 2 MB
  float*          w0x = (float*)(ws + 52428800);               // 8 KB
  float*          bx  = (float*)(ws + 52436992);               // 8 KB
  float*          wpp = (float*)(ws + 52445184);               // 18 KB
  float*          u   = (float*)(ws + 52463616);               // 576 KB (16*9*1024 f32)

  hipMemsetAsync(h0, 0, 16777216, stream);
  hipMemsetAsync(Cst, 0, 16777216, stream);
  repack_w<<<4096, 256, 0, stream>>>(Wconv, bconv, Wp, w0x, bx);
  repack_wpost<<<18, 256, 0, stream>>>(Wpost, wpp);

  unsigned short* hp = h0;
  unsigned short* hn = h1;
  for (int t = 0; t < T_; ++t) {
    lstm_step<<<1024, 256, 0, stream>>>(Wp, hp, hn, Cst, w0x, bx, x, t);
    conv_u<<<4096, 256, 0, stream>>>(hn, wpp, u);
    conv_st<<<64, 256, 0, stream>>>(u, bpost, out, t);
    unsigned short* tmp = hp; hp = hn; hn = tmp;
  }
}